// Round 1
// baseline (1185.364 us; speedup 1.0000x reference)
//
#include <hip/hip_runtime.h>

#define Nn 8
#define Cc 256
#define C8 32
#define Hh 56
#define Ww 56
#define HW 3136
#define CHW (Cc * HW)          // 802816
#define K9C 2304
#define S_HW (1.0f / 56.0f)    // 1/sqrt(H*W), sqrt(3136)=56
#define S_C  0.0625f           // 1/sqrt(C),   sqrt(256)=16

typedef float f4 __attribute__((ext_vector_type(4)));

// ---------------------------------------------------------------- t3 = (p2*x)^2
__global__ __launch_bounds__(256) void k_t3(const float* __restrict__ x,
                                            const float* __restrict__ p2,
                                            float* __restrict__ t3) {
    int g = blockIdx.x * 256 + threadIdx.x;
    int idx = g * 4;
    int pidx = idx % CHW;                       // p2 broadcast over n; CHW%4==0
    f4 xv = *(const f4*)(x + idx);
    f4 pv = *(const f4*)(p2 + pidx);
    f4 t = xv * pv;
    *(f4*)(t3 + idx) = t * t;
}

// ------------------------------------------- t5 = softmax_h(roll(t3,+1h,-1w))
// softmax over h of rolled data == rolled softmax of original columns.
__global__ __launch_bounds__(256) void k_softmax(const float* __restrict__ t3,
                                                 float* __restrict__ t5) {
    __shared__ float ld[HW];
    __shared__ float mx[Ww], rs[Ww];
    int tid = threadIdx.x;
    const float* src = t3 + (size_t)blockIdx.x * HW;   // blockIdx.x = n*C + c
    for (int i = tid; i < HW; i += 256) ld[i] = src[i];
    __syncthreads();
    if (tid < Ww) {
        float m = -1e30f;
        for (int h = 0; h < Hh; h++) m = fmaxf(m, ld[h * Ww + tid]);
        float s = 0.f;
        for (int h = 0; h < Hh; h++) s += __expf(ld[h * Ww + tid] - m);
        mx[tid] = m;
        rs[tid] = 1.0f / s;
    }
    __syncthreads();
    float* dst = t5 + (size_t)blockIdx.x * HW;
    for (int i = tid; i < HW; i += 256) {
        int h = i / Ww, w = i - h * Ww;
        int wp = (w + 1 == Ww) ? 0 : w + 1;     // t4[h][w] = t3[(h-1)%H][(w+1)%W]
        int hp = (h == 0) ? Hh - 1 : h - 1;
        dst[i] = __expf(ld[hp * Ww + wp] - mx[wp]) * rs[wp];
    }
}

// --------------------------------- t7[n,o,s] = sum_{c,i,j} w7[o,9c+3i+j]*x_shift
__global__ __launch_bounds__(256) void k_gemm_t7(const float* __restrict__ x,
                                                 const float* __restrict__ w7,
                                                 float* __restrict__ t7) {
    __shared__ float As[64][20];
    __shared__ float Bs[16][68];
    int tid = threadIdx.x;
    int tx = tid & 15, ty = tid >> 4;
    int n = blockIdx.z;
    int s0 = blockIdx.x * 64;
    int o0 = blockIdx.y * 64;
    const float* xn = x + (size_t)n * CHW;
    f4 acc[4] = {};
    for (int kt = 0; kt < K9C; kt += 16) {
        {   // A tile: w7[o0+r][kt+kq], coalesced float4
            int lin = tid * 4;
            int r = lin >> 4, kq = lin & 15;
            *(f4*)(&As[r][kq]) = *(const f4*)(w7 + (size_t)(o0 + r) * K9C + kt + kq);
        }
#pragma unroll
        for (int e = 0; e < 4; e++) {           // B tile: gathered im2col
            int lin = tid + e * 256;
            int kk = lin >> 6, col = lin & 63;
            int k = kt + kk;
            int c = k / 9;
            int r9 = k - c * 9;
            int i3 = r9 / 3;
            int j3 = r9 - i3 * 3;
            int s = s0 + col;
            int h = s / Ww, w = s - h * Ww;
            int hh = h + 3 * i3 - 3;
            int ww = w + 3 * j3 - 3;
            float v = 0.f;
            if ((unsigned)hh < (unsigned)Hh && (unsigned)ww < (unsigned)Ww)
                v = xn[c * HW + hh * Ww + ww];
            Bs[kk][col] = v;
        }
        __syncthreads();
#pragma unroll
        for (int kk = 0; kk < 16; kk += 4) {
            f4 av[4], bv[4];
#pragma unroll
            for (int a = 0; a < 4; a++) av[a] = *(const f4*)(&As[ty * 4 + a][kk]);
#pragma unroll
            for (int q = 0; q < 4; q++) bv[q] = *(const f4*)(&Bs[kk + q][tx * 4]);
#pragma unroll
            for (int a = 0; a < 4; a++)
#pragma unroll
                for (int q = 0; q < 4; q++) acc[a] += av[a][q] * bv[q];
        }
        __syncthreads();
    }
    float* outp = t7 + (size_t)n * CHW;
#pragma unroll
    for (int a = 0; a < 4; a++) {
        int o = o0 + ty * 4 + a;
        *(f4*)(outp + (size_t)o * HW + s0 + tx * 4) = acc[a];
    }
}

// ------------------- t17 = t3 - w15 @ roll(x,+1,h)   (t15 fused-subtracted)
__global__ __launch_bounds__(256) void k_gemm_t15(const float* __restrict__ x,
                                                  const float* __restrict__ w15,
                                                  const float* __restrict__ t3,
                                                  float* __restrict__ t17) {
    __shared__ float As[64][20];
    __shared__ float Bs[16][68];
    int tid = threadIdx.x;
    int tx = tid & 15, ty = tid >> 4;
    int n = blockIdx.z;
    int s0 = blockIdx.x * 64;
    int o0 = blockIdx.y * 64;
    const float* xn = x + (size_t)n * CHW;
    f4 acc[4] = {};
    for (int kt = 0; kt < Cc; kt += 16) {
        {
            int lin = tid * 4;
            int r = lin >> 4, kq = lin & 15;
            *(f4*)(&As[r][kq]) = *(const f4*)(w15 + (size_t)(o0 + r) * Cc + kt + kq);
        }
#pragma unroll
        for (int e = 0; e < 4; e++) {
            int lin = tid + e * 256;
            int kk = lin >> 6, col = lin & 63;
            int c = kt + kk;
            int s = s0 + col;
            int h = s / Ww, w = s - h * Ww;
            int hp = (h == 0) ? Hh - 1 : h - 1;   // t14 = roll(x,+1,h)
            Bs[kk][col] = xn[c * HW + hp * Ww + w];
        }
        __syncthreads();
#pragma unroll
        for (int kk = 0; kk < 16; kk += 4) {
            f4 av[4], bv[4];
#pragma unroll
            for (int a = 0; a < 4; a++) av[a] = *(const f4*)(&As[ty * 4 + a][kk]);
#pragma unroll
            for (int q = 0; q < 4; q++) bv[q] = *(const f4*)(&Bs[kk + q][tx * 4]);
#pragma unroll
            for (int a = 0; a < 4; a++)
#pragma unroll
                for (int q = 0; q < 4; q++) acc[a] += av[a][q] * bv[q];
        }
        __syncthreads();
    }
    const float* t3n = t3 + (size_t)n * CHW;
    float* outp = t17 + (size_t)n * CHW;
#pragma unroll
    for (int a = 0; a < 4; a++) {
        size_t idx = (size_t)(o0 + ty * 4 + a) * HW + s0 + tx * 4;
        f4 t3v = *(const f4*)(t3n + idx);
        *(f4*)(outp + idx) = t3v - acc[a];
    }
}

// ----------- out[n,c,d] += scale * sum_s A[n,c,s]*B[(n,)d,s]  (A·B^T, split-K)
// used for t8 (A=t5, B=t3) and u (A=t17, B=p16 broadcast: Bn=0)
__global__ __launch_bounds__(256) void k_gemm_abt(const float* __restrict__ A,
                                                  const float* __restrict__ B,
                                                  long Bn,
                                                  float* __restrict__ outp,
                                                  float scale) {
    __shared__ float As[64][20];
    __shared__ float Bs[64][20];
    int tid = threadIdx.x;
    int tx = tid & 15, ty = tid >> 4;
    int z = blockIdx.z;
    int n = z / 7, ks = z - n * 7;              // 7-way split-K, 3136 = 7*448
    int d0 = blockIdx.x * 64;
    int c0 = blockIdx.y * 64;
    const float* An = A + (size_t)n * CHW;
    const float* Bb = B + (size_t)n * Bn;
    float acc[4][4] = {};
    int ktbeg = ks * 448;
    for (int kt = ktbeg; kt < ktbeg + 448; kt += 16) {
        int lin = tid * 4;
        int r = lin >> 4, kq = lin & 15;
        *(f4*)(&As[r][kq]) = *(const f4*)(An + (size_t)(c0 + r) * HW + kt + kq);
        *(f4*)(&Bs[r][kq]) = *(const f4*)(Bb + (size_t)(d0 + r) * HW + kt + kq);
        __syncthreads();
#pragma unroll
        for (int kk = 0; kk < 16; kk += 4) {
            f4 av[4], bv[4];
#pragma unroll
            for (int a = 0; a < 4; a++) av[a] = *(const f4*)(&As[ty * 4 + a][kk]);
#pragma unroll
            for (int b = 0; b < 4; b++) bv[b] = *(const f4*)(&Bs[tx * 4 + b][kk]);
#pragma unroll
            for (int a = 0; a < 4; a++)
#pragma unroll
                for (int b = 0; b < 4; b++)
                    acc[a][b] += av[a][0] * bv[b][0] + av[a][1] * bv[b][1] +
                                 av[a][2] * bv[b][2] + av[a][3] * bv[b][3];
        }
        __syncthreads();
    }
    float* on = outp + (size_t)n * (Cc * Cc);
#pragma unroll
    for (int a = 0; a < 4; a++)
#pragma unroll
        for (int b = 0; b < 4; b++)
            atomicAdd(&on[(size_t)(c0 + ty * 4 + a) * Cc + d0 + tx * 4 + b],
                      acc[a][b] * scale);
}

// ---------------- t19[n,c,d] = s_hw * sum_b u[n,c,b] * t8[n,b,d]   (256^3)
__global__ __launch_bounds__(256) void k_gemm_t19(const float* __restrict__ u,
                                                  const float* __restrict__ t8,
                                                  float* __restrict__ t19) {
    __shared__ float As[64][20];
    __shared__ float Bs[16][68];
    int tid = threadIdx.x;
    int tx = tid & 15, ty = tid >> 4;
    int n = blockIdx.z;
    int d0 = blockIdx.x * 64;
    int c0 = blockIdx.y * 64;
    const float* un = u + (size_t)n * Cc * Cc;
    const float* t8n = t8 + (size_t)n * Cc * Cc;
    f4 acc[4] = {};
    for (int kt = 0; kt < Cc; kt += 16) {
        int lin = tid * 4;
        {
            int r = lin >> 4, kq = lin & 15;
            *(f4*)(&As[r][kq]) = *(const f4*)(un + (size_t)(c0 + r) * Cc + kt + kq);
        }
        {
            int kk = lin >> 6, col = lin & 63;
            *(f4*)(&Bs[kk][col]) = *(const f4*)(t8n + (size_t)(kt + kk) * Cc + d0 + col);
        }
        __syncthreads();
#pragma unroll
        for (int kk = 0; kk < 16; kk += 4) {
            f4 av[4], bv[4];
#pragma unroll
            for (int a = 0; a < 4; a++) av[a] = *(const f4*)(&As[ty * 4 + a][kk]);
#pragma unroll
            for (int q = 0; q < 4; q++) bv[q] = *(const f4*)(&Bs[kk + q][tx * 4]);
#pragma unroll
            for (int a = 0; a < 4; a++)
#pragma unroll
                for (int q = 0; q < 4; q++) acc[a] += av[a][q] * bv[q];
        }
        __syncthreads();
    }
    float* on = t19 + (size_t)n * Cc * Cc;
#pragma unroll
    for (int a = 0; a < 4; a++)
        *(f4*)(on + (size_t)(c0 + ty * 4 + a) * Cc + d0 + tx * 4) = acc[a] * S_HW;
}

// -------- t11[n,s] = sum_b p11[b]*p9[b,s]*(sum_c w6[b,c]*t3[n,c,s])  (t6/t9 fused)
__global__ __launch_bounds__(256) void k_t11(const float* __restrict__ t3,
                                             const float* __restrict__ w6,
                                             const float* __restrict__ p9,
                                             const float* __restrict__ p11,
                                             float* __restrict__ t11) {
    __shared__ float w6s[C8 * Cc];              // 32 KiB
    int tid = threadIdx.x;
    for (int i = tid; i < C8 * Cc; i += 256) w6s[i] = w6[i];
    __syncthreads();
    int g = blockIdx.x * 256 + tid;             // 0..25087
    int n = g / HW;
    int s = g - n * HW;
    const float* t3n = t3 + (size_t)n * CHW + s;
    float acc[C8] = {};
    for (int c = 0; c < Cc; c += 4) {
        float v0 = t3n[(c + 0) * HW];
        float v1 = t3n[(c + 1) * HW];
        float v2 = t3n[(c + 2) * HW];
        float v3 = t3n[(c + 3) * HW];
#pragma unroll
        for (int b = 0; b < C8; b++) {
            f4 wv = *(const f4*)(&w6s[b * Cc + c]);
            acc[b] += wv[0] * v0 + wv[1] * v1 + wv[2] * v2 + wv[3] * v3;
        }
    }
    float r = 0.f;
#pragma unroll
    for (int b = 0; b < C8; b++) r += p11[b] * p9[b * HW + s] * acc[b];
    t11[g] = r;
}

// ------- t13 = t11 - depthwise_conv(max(t5,t7), w12, kh in {-2,0,+2})
__global__ __launch_bounds__(256) void k_t13(const float* __restrict__ t5,
                                             const float* __restrict__ t7,
                                             const float* __restrict__ t11,
                                             const float* __restrict__ w12,
                                             float* __restrict__ t13) {
    int g = blockIdx.x * 256 + threadIdx.x;     // over N*C*HW
    int s = g % HW;
    int nc = g / HW;
    int c = nc % Cc;
    int n = nc / Cc;
    int h = s / Ww, w = s - h * Ww;
    float sum = 0.f;
#pragma unroll
    for (int kh = 0; kh < 3; kh++) {
        int hh = h - 2 + 2 * kh;
        if ((unsigned)hh < (unsigned)Hh) {
            size_t idx = (size_t)nc * HW + hh * Ww + w;
            float t10 = fmaxf(t5[idx], t7[idx]);
            sum += w12[c * 3 + kh] * t10;
        }
    }
    t13[g] = t11[(size_t)n * HW + s] - sum;
}

// -------- out[n,c,s] = s_c * sum_d t19[n,d,c]*t13[n,d,s] + t7[n,c,s]*t17[n,c,s]
__global__ __launch_bounds__(256) void k_gemm_out(const float* __restrict__ t19,
                                                  const float* __restrict__ t13,
                                                  const float* __restrict__ t7,
                                                  const float* __restrict__ t17,
                                                  float* __restrict__ outp) {
    __shared__ float As[64][20];
    __shared__ float Bs[16][68];
    int tid = threadIdx.x;
    int tx = tid & 15, ty = tid >> 4;
    int n = blockIdx.z;
    int s0 = blockIdx.x * 64;
    int c0 = blockIdx.y * 64;
    const float* t19n = t19 + (size_t)n * Cc * Cc;
    const float* t13n = t13 + (size_t)n * CHW;
    f4 acc[4] = {};
    for (int kt = 0; kt < Cc; kt += 16) {
        int lin = tid * 4;
        {   // A = t19^T : transpose on load
            int kk = lin >> 6, cc = lin & 63;
            f4 v = *(const f4*)(t19n + (size_t)(kt + kk) * Cc + c0 + cc);
            As[cc + 0][kk] = v[0];
            As[cc + 1][kk] = v[1];
            As[cc + 2][kk] = v[2];
            As[cc + 3][kk] = v[3];
        }
        {
            int kk = lin >> 6, col = lin & 63;
            *(f4*)(&Bs[kk][col]) = *(const f4*)(t13n + (size_t)(kt + kk) * HW + s0 + col);
        }
        __syncthreads();
#pragma unroll
        for (int kk = 0; kk < 16; kk += 4) {
            f4 av[4], bv[4];
#pragma unroll
            for (int a = 0; a < 4; a++) av[a] = *(const f4*)(&As[ty * 4 + a][kk]);
#pragma unroll
            for (int q = 0; q < 4; q++) bv[q] = *(const f4*)(&Bs[kk + q][tx * 4]);
#pragma unroll
            for (int a = 0; a < 4; a++)
#pragma unroll
                for (int q = 0; q < 4; q++) acc[a] += av[a][q] * bv[q];
        }
        __syncthreads();
    }
    const float* t7n = t7 + (size_t)n * CHW;
    const float* t17n = t17 + (size_t)n * CHW;
    float* on = outp + (size_t)n * CHW;
#pragma unroll
    for (int a = 0; a < 4; a++) {
        size_t idx = (size_t)(c0 + ty * 4 + a) * HW + s0 + tx * 4;
        f4 t7v = *(const f4*)(t7n + idx);
        f4 t17v = *(const f4*)(t17n + idx);
        f4 o = acc[a] * S_C + t7v * t17v;
        *(f4*)(on + idx) = o;
    }
}

extern "C" void kernel_launch(void* const* d_in, const int* in_sizes, int n_in,
                              void* d_out, int out_size, void* d_ws, size_t ws_size,
                              hipStream_t stream) {
    const float* x   = (const float*)d_in[0];
    const float* p2  = (const float*)d_in[1];
    const float* w6  = (const float*)d_in[2];
    const float* w7  = (const float*)d_in[3];
    const float* p9  = (const float*)d_in[4];
    const float* p11 = (const float*)d_in[5];
    const float* w12 = (const float*)d_in[6];
    const float* w15 = (const float*)d_in[7];
    const float* p16 = (const float*)d_in[8];
    float* ws = (float*)d_ws;

    float* t3  = ws;                        // 6422528 floats
    float* t5  = ws + 6422528;
    float* t7  = ws + 12845056;
    float* t17 = ws + 19267584;
    float* t13 = t3;                        // t3 dead after k_t11/k_gemm_abt(t8)
    float* t8  = ws + 25690112;             // 8*256*256
    float* uu  = ws + 26214400;
    float* t19 = ws + 26738688;
    float* t11 = ws + 27262976;             // 8*3136
    float* outp = (float*)d_out;

    k_t3<<<dim3(6272), dim3(256), 0, stream>>>(x, p2, t3);
    k_softmax<<<dim3(Nn * Cc), dim3(256), 0, stream>>>(t3, t5);
    hipMemsetAsync(t8, 0, (size_t)Nn * Cc * Cc * 4, stream);   // split-K accumulators
    hipMemsetAsync(uu, 0, (size_t)Nn * Cc * Cc * 4, stream);
    k_gemm_t7<<<dim3(49, 4, Nn), dim3(256), 0, stream>>>(x, w7, t7);
    k_gemm_t15<<<dim3(49, 4, Nn), dim3(256), 0, stream>>>(x, w15, t3, t17);
    k_gemm_abt<<<dim3(4, 4, Nn * 7), dim3(256), 0, stream>>>(t5, t3, (long)CHW, t8, S_HW);
    k_t11<<<dim3(98), dim3(256), 0, stream>>>(t3, w6, p9, p11, t11);
    k_gemm_abt<<<dim3(4, 4, Nn * 7), dim3(256), 0, stream>>>(t17, p16, 0L, uu, 1.0f);
    k_gemm_t19<<<dim3(4, 4, Nn), dim3(256), 0, stream>>>(uu, t8, t19);
    k_t13<<<dim3(25088), dim3(256), 0, stream>>>(t5, t7, t11, w12, t13);
    k_gemm_out<<<dim3(49, 4, Nn), dim3(256), 0, stream>>>(t19, t13, t7, t17, outp);
}

// Round 2
// 683.732 us; speedup vs baseline: 1.7337x; 1.7337x over previous
//
#include <hip/hip_runtime.h>

#define Nn 8
#define Cc 256
#define C8 32
#define Hh 56
#define Ww 56
#define HW 3136
#define CHW (Cc * HW)          // 802816
#define K9C 2304
#define S_HW (1.0f / 56.0f)    // 1/sqrt(H*W)
#define S_C  0.0625f           // 1/sqrt(C)
#define XPLANE 3844            // 62*62 padded plane
#define XPAD_ELEMS (Nn * Cc * XPLANE)

typedef float f4 __attribute__((ext_vector_type(4)));
typedef unsigned short ushort;
typedef __attribute__((ext_vector_type(8))) unsigned short u16x8;
typedef __attribute__((ext_vector_type(8))) short short8;   // bf16 MFMA frag
typedef __attribute__((ext_vector_type(4))) float floatx4;

__device__ __forceinline__ ushort f2bf(float f) {   // RNE
    union { float f; unsigned u; } v; v.f = f;
    unsigned r = v.u + 0x7FFF + ((v.u >> 16) & 1);
    return (ushort)(r >> 16);
}

// ---------------------------------------------------------------- t3 = (p2*x)^2
__global__ __launch_bounds__(256) void k_t3(const float* __restrict__ x,
                                            const float* __restrict__ p2,
                                            float* __restrict__ t3) {
    int g = blockIdx.x * 256 + threadIdx.x;
    int idx = g * 4;
    int pidx = idx % CHW;
    f4 xv = *(const f4*)(x + idx);
    f4 pv = *(const f4*)(p2 + pidx);
    f4 t = xv * pv;
    *(f4*)(t3 + idx) = t * t;
}

// -------------------------------- xp: zero-padded bf16 copy of x (n,c,62,62)
__global__ __launch_bounds__(256) void k_xpad(const float* __restrict__ x,
                                              ushort* __restrict__ xp) {
    int g = blockIdx.x * 256 + threadIdx.x;       // over N*C*H*W
    int nc = g / HW;
    int s = g - nc * HW;
    int h = s / Ww, w = s - h * Ww;
    xp[(size_t)nc * XPLANE + (h + 3) * 62 + (w + 3)] = f2bf(x[g]);
}

// -------------------------------- w7 -> bf16
__global__ __launch_bounds__(256) void k_w7b(const float* __restrict__ w7,
                                             ushort* __restrict__ w7b) {
    int g = blockIdx.x * 256 + threadIdx.x;       // over 256*2304
    w7b[g] = f2bf(w7[g]);
}

// ------------------------------------------- t5 = softmax_h(roll(t3,+1h,-1w))
__global__ __launch_bounds__(256) void k_softmax(const float* __restrict__ t3,
                                                 float* __restrict__ t5) {
    __shared__ float ld[HW];
    __shared__ float mx[Ww], rs[Ww];
    int tid = threadIdx.x;
    const float* src = t3 + (size_t)blockIdx.x * HW;
    for (int i = tid; i < HW; i += 256) ld[i] = src[i];
    __syncthreads();
    if (tid < Ww) {
        float m = -1e30f;
        for (int h = 0; h < Hh; h++) m = fmaxf(m, ld[h * Ww + tid]);
        float s = 0.f;
        for (int h = 0; h < Hh; h++) s += __expf(ld[h * Ww + tid] - m);
        mx[tid] = m;
        rs[tid] = 1.0f / s;
    }
    __syncthreads();
    float* dst = t5 + (size_t)blockIdx.x * HW;
    for (int i = tid; i < HW; i += 256) {
        int h = i / Ww, w = i - h * Ww;
        int wp = (w + 1 == Ww) ? 0 : w + 1;
        int hp = (h == 0) ? Hh - 1 : h - 1;
        dst[i] = __expf(ld[hp * Ww + wp] - mx[wp]) * rs[wp];
    }
}

// --------------------- t7 = w7 @ im2col(x)  — bf16 MFMA, 128x128 tile
__global__ __launch_bounds__(256) void k_gemm_t7_mfma(const ushort* __restrict__ xp,
                                                      const ushort* __restrict__ w7b,
                                                      float* __restrict__ t7) {
    __shared__ __align__(16) ushort As[128][40];   // [m][k], pad 32->40
    __shared__ __align__(16) ushort Bs[128][40];   // [s][k], pad 32->40
    int tid = threadIdx.x;
    int lane = tid & 63;
    int ln15 = lane & 15;
    int quad = lane >> 4;
    int wave = tid >> 6;
    int wm64 = (wave >> 1) * 64;
    int wn64 = (wave & 1) * 64;
    int n = blockIdx.z;
    int s0 = blockIdx.x * 128;
    int o0 = blockIdx.y * 128;
    const ushort* xpn = xp + (size_t)n * Cc * XPLANE;

    // B-staging geometry (fixed per thread)
    int s_l = tid & 127;
    int kgrp = (tid >> 7) * 16;                    // wave-uniform
    int s_g = s0 + s_l;
    int sc = s_g < HW ? s_g : HW - 1;
    int h = sc / Ww, w = sc - h * Ww;
    int hw62 = h * 62 + w;                         // +3 border folded into koff

    floatx4 acc[4][4] = {};

    for (int kt = 0; kt < K9C; kt += 32) {
        // ---- stage A: w7b rows o0..o0+127, k kt..kt+31
#pragma unroll
        for (int e = 0; e < 2; e++) {
            int lin = tid + e * 256;
            int m = lin >> 2, kq = (lin & 3) * 8;
            u16x8 av = *(const u16x8*)(w7b + (size_t)(o0 + m) * K9C + kt + kq);
            *(u16x8*)(&As[m][kq]) = av;
        }
        // ---- stage B: affine im2col gather from padded bf16 x
        ushort vb[16];
#pragma unroll
        for (int u = 0; u < 16; u++) {
            int k = kt + kgrp + u;                 // wave-uniform
            int c = k / 9;
            int r9 = k - 9 * c;
            int i3 = r9 / 3;
            int j3 = r9 - 3 * i3;
            int koff = c * XPLANE + i3 * 186 + j3 * 3;
            vb[u] = xpn[koff + hw62];
        }
        u16x8 b0 = { vb[0], vb[1], vb[2],  vb[3],  vb[4],  vb[5],  vb[6],  vb[7]  };
        u16x8 b1 = { vb[8], vb[9], vb[10], vb[11], vb[12], vb[13], vb[14], vb[15] };
        *(u16x8*)(&Bs[s_l][kgrp])     = b0;
        *(u16x8*)(&Bs[s_l][kgrp + 8]) = b1;
        __syncthreads();

        // ---- compute
        short8 af[4], bf[4];
#pragma unroll
        for (int a = 0; a < 4; a++)
            af[a] = *(const short8*)(&As[wm64 + a * 16 + ln15][quad * 8]);
#pragma unroll
        for (int b = 0; b < 4; b++)
            bf[b] = *(const short8*)(&Bs[wn64 + b * 16 + ln15][quad * 8]);
#pragma unroll
        for (int a = 0; a < 4; a++)
#pragma unroll
            for (int b = 0; b < 4; b++)
                acc[a][b] = __builtin_amdgcn_mfma_f32_16x16x32_bf16(
                    af[a], bf[b], acc[a][b], 0, 0, 0);
        __syncthreads();
    }

    // ---- epilogue: D row=(quad*4+reg), col=ln15
    float* t7n = t7 + (size_t)n * CHW;
#pragma unroll
    for (int a = 0; a < 4; a++) {
        int obase = o0 + wm64 + a * 16 + quad * 4;
#pragma unroll
        for (int b = 0; b < 4; b++) {
            int s = s0 + wn64 + b * 16 + ln15;
            if (s < HW) {
#pragma unroll
                for (int r = 0; r < 4; r++)
                    t7n[(size_t)(obase + r) * HW + s] = acc[a][b][r];
            }
        }
    }
}

// ------------------- t17 = t3 - w15 @ roll(x,+1,h)
__global__ __launch_bounds__(256) void k_gemm_t15(const float* __restrict__ x,
                                                  const float* __restrict__ w15,
                                                  const float* __restrict__ t3,
                                                  float* __restrict__ t17) {
    __shared__ float As[64][20];
    __shared__ float Bs[16][68];
    int tid = threadIdx.x;
    int tx = tid & 15, ty = tid >> 4;
    int n = blockIdx.z;
    int s0 = blockIdx.x * 64;
    int o0 = blockIdx.y * 64;
    const float* xn = x + (size_t)n * CHW;
    f4 acc[4] = {};
    for (int kt = 0; kt < Cc; kt += 16) {
        {
            int lin = tid * 4;
            int r = lin >> 4, kq = lin & 15;
            *(f4*)(&As[r][kq]) = *(const f4*)(w15 + (size_t)(o0 + r) * Cc + kt + kq);
        }
#pragma unroll
        for (int e = 0; e < 4; e++) {
            int lin = tid + e * 256;
            int kk = lin >> 6, col = lin & 63;
            int c = kt + kk;
            int s = s0 + col;
            int h = s / Ww, w = s - h * Ww;
            int hp = (h == 0) ? Hh - 1 : h - 1;
            Bs[kk][col] = xn[c * HW + hp * Ww + w];
        }
        __syncthreads();
#pragma unroll
        for (int kk = 0; kk < 16; kk += 4) {
            f4 av[4], bv[4];
#pragma unroll
            for (int a = 0; a < 4; a++) av[a] = *(const f4*)(&As[ty * 4 + a][kk]);
#pragma unroll
            for (int q = 0; q < 4; q++) bv[q] = *(const f4*)(&Bs[kk + q][tx * 4]);
#pragma unroll
            for (int a = 0; a < 4; a++)
#pragma unroll
                for (int q = 0; q < 4; q++) acc[a] += av[a][q] * bv[q];
        }
        __syncthreads();
    }
    const float* t3n = t3 + (size_t)n * CHW;
    float* outp = t17 + (size_t)n * CHW;
#pragma unroll
    for (int a = 0; a < 4; a++) {
        size_t idx = (size_t)(o0 + ty * 4 + a) * HW + s0 + tx * 4;
        f4 t3v = *(const f4*)(t3n + idx);
        *(f4*)(outp + idx) = t3v - acc[a];
    }
}

// ----------- out[n,c,d] += scale * sum_s A[n,c,s]*B[(n,)d,s]  (split-K)
__global__ __launch_bounds__(256) void k_gemm_abt(const float* __restrict__ A,
                                                  const float* __restrict__ B,
                                                  long Bn,
                                                  float* __restrict__ outp,
                                                  float scale) {
    __shared__ float As[64][20];
    __shared__ float Bs[64][20];
    int tid = threadIdx.x;
    int tx = tid & 15, ty = tid >> 4;
    int z = blockIdx.z;
    int n = z / 7, ks = z - n * 7;
    int d0 = blockIdx.x * 64;
    int c0 = blockIdx.y * 64;
    const float* An = A + (size_t)n * CHW;
    const float* Bb = B + (size_t)n * Bn;
    float acc[4][4] = {};
    int ktbeg = ks * 448;
    for (int kt = ktbeg; kt < ktbeg + 448; kt += 16) {
        int lin = tid * 4;
        int r = lin >> 4, kq = lin & 15;
        *(f4*)(&As[r][kq]) = *(const f4*)(An + (size_t)(c0 + r) * HW + kt + kq);
        *(f4*)(&Bs[r][kq]) = *(const f4*)(Bb + (size_t)(d0 + r) * HW + kt + kq);
        __syncthreads();
#pragma unroll
        for (int kk = 0; kk < 16; kk += 4) {
            f4 av[4], bv[4];
#pragma unroll
            for (int a = 0; a < 4; a++) av[a] = *(const f4*)(&As[ty * 4 + a][kk]);
#pragma unroll
            for (int b = 0; b < 4; b++) bv[b] = *(const f4*)(&Bs[tx * 4 + b][kk]);
#pragma unroll
            for (int a = 0; a < 4; a++)
#pragma unroll
                for (int b = 0; b < 4; b++)
                    acc[a][b] += av[a][0] * bv[b][0] + av[a][1] * bv[b][1] +
                                 av[a][2] * bv[b][2] + av[a][3] * bv[b][3];
        }
        __syncthreads();
    }
    float* on = outp + (size_t)n * (Cc * Cc);
#pragma unroll
    for (int a = 0; a < 4; a++)
#pragma unroll
        for (int b = 0; b < 4; b++)
            atomicAdd(&on[(size_t)(c0 + ty * 4 + a) * Cc + d0 + tx * 4 + b],
                      acc[a][b] * scale);
}

// ---------------- t19[n,c,d] = s_hw * sum_b u[n,c,b] * t8[n,b,d]
__global__ __launch_bounds__(256) void k_gemm_t19(const float* __restrict__ u,
                                                  const float* __restrict__ t8,
                                                  float* __restrict__ t19) {
    __shared__ float As[64][20];
    __shared__ float Bs[16][68];
    int tid = threadIdx.x;
    int tx = tid & 15, ty = tid >> 4;
    int n = blockIdx.z;
    int d0 = blockIdx.x * 64;
    int c0 = blockIdx.y * 64;
    const float* un = u + (size_t)n * Cc * Cc;
    const float* t8n = t8 + (size_t)n * Cc * Cc;
    f4 acc[4] = {};
    for (int kt = 0; kt < Cc; kt += 16) {
        int lin = tid * 4;
        {
            int r = lin >> 4, kq = lin & 15;
            *(f4*)(&As[r][kq]) = *(const f4*)(un + (size_t)(c0 + r) * Cc + kt + kq);
        }
        {
            int kk = lin >> 6, col = lin & 63;
            *(f4*)(&Bs[kk][col]) = *(const f4*)(t8n + (size_t)(kt + kk) * Cc + d0 + col);
        }
        __syncthreads();
#pragma unroll
        for (int kk = 0; kk < 16; kk += 4) {
            f4 av[4], bv[4];
#pragma unroll
            for (int a = 0; a < 4; a++) av[a] = *(const f4*)(&As[ty * 4 + a][kk]);
#pragma unroll
            for (int q = 0; q < 4; q++) bv[q] = *(const f4*)(&Bs[kk + q][tx * 4]);
#pragma unroll
            for (int a = 0; a < 4; a++)
#pragma unroll
                for (int q = 0; q < 4; q++) acc[a] += av[a][q] * bv[q];
        }
        __syncthreads();
    }
    float* on = t19 + (size_t)n * Cc * Cc;
#pragma unroll
    for (int a = 0; a < 4; a++)
        *(f4*)(on + (size_t)(c0 + ty * 4 + a) * Cc + d0 + tx * 4) = acc[a] * S_HW;
}

// -------- t11[n,s] = sum_b p11[b]*p9[b,s]*(sum_c w6[b,c]*t3[n,c,s])
__global__ __launch_bounds__(256) void k_t11(const float* __restrict__ t3,
                                             const float* __restrict__ w6,
                                             const float* __restrict__ p9,
                                             const float* __restrict__ p11,
                                             float* __restrict__ t11) {
    __shared__ float w6s[C8 * Cc];
    int tid = threadIdx.x;
    for (int i = tid; i < C8 * Cc; i += 256) w6s[i] = w6[i];
    __syncthreads();
    int g = blockIdx.x * 256 + tid;
    int n = g / HW;
    int s = g - n * HW;
    const float* t3n = t3 + (size_t)n * CHW + s;
    float acc[C8] = {};
    for (int c = 0; c < Cc; c += 4) {
        float v0 = t3n[(c + 0) * HW];
        float v1 = t3n[(c + 1) * HW];
        float v2 = t3n[(c + 2) * HW];
        float v3 = t3n[(c + 3) * HW];
#pragma unroll
        for (int b = 0; b < C8; b++) {
            f4 wv = *(const f4*)(&w6s[b * Cc + c]);
            acc[b] += wv[0] * v0 + wv[1] * v1 + wv[2] * v2 + wv[3] * v3;
        }
    }
    float r = 0.f;
#pragma unroll
    for (int b = 0; b < C8; b++) r += p11[b] * p9[b * HW + s] * acc[b];
    t11[g] = r;
}

// ------- t13 = t11 - depthwise_conv(max(t5,t7), w12)
__global__ __launch_bounds__(256) void k_t13(const float* __restrict__ t5,
                                             const float* __restrict__ t7,
                                             const float* __restrict__ t11,
                                             const float* __restrict__ w12,
                                             float* __restrict__ t13) {
    int g = blockIdx.x * 256 + threadIdx.x;
    int s = g % HW;
    int nc = g / HW;
    int c = nc % Cc;
    int n = nc / Cc;
    int h = s / Ww, w = s - h * Ww;
    float sum = 0.f;
#pragma unroll
    for (int kh = 0; kh < 3; kh++) {
        int hh = h - 2 + 2 * kh;
        if ((unsigned)hh < (unsigned)Hh) {
            size_t idx = (size_t)nc * HW + hh * Ww + w;
            float t10 = fmaxf(t5[idx], t7[idx]);
            sum += w12[c * 3 + kh] * t10;
        }
    }
    t13[g] = t11[(size_t)n * HW + s] - sum;
}

// -------- out[n,c,s] = s_c * sum_d t19[n,d,c]*t13[n,d,s] + t7*t17
__global__ __launch_bounds__(256) void k_gemm_out(const float* __restrict__ t19,
                                                  const float* __restrict__ t13,
                                                  const float* __restrict__ t7,
                                                  const float* __restrict__ t17,
                                                  float* __restrict__ outp) {
    __shared__ float As[64][20];
    __shared__ float Bs[16][68];
    int tid = threadIdx.x;
    int tx = tid & 15, ty = tid >> 4;
    int n = blockIdx.z;
    int s0 = blockIdx.x * 64;
    int c0 = blockIdx.y * 64;
    const float* t19n = t19 + (size_t)n * Cc * Cc;
    const float* t13n = t13 + (size_t)n * CHW;
    f4 acc[4] = {};
    for (int kt = 0; kt < Cc; kt += 16) {
        int lin = tid * 4;
        {
            int kk = lin >> 6, cc = lin & 63;
            f4 v = *(const f4*)(t19n + (size_t)(kt + kk) * Cc + c0 + cc);
            As[cc + 0][kk] = v[0];
            As[cc + 1][kk] = v[1];
            As[cc + 2][kk] = v[2];
            As[cc + 3][kk] = v[3];
        }
        {
            int kk = lin >> 6, col = lin & 63;
            *(f4*)(&Bs[kk][col]) = *(const f4*)(t13n + (size_t)(kt + kk) * HW + s0 + col);
        }
        __syncthreads();
#pragma unroll
        for (int kk = 0; kk < 16; kk += 4) {
            f4 av[4], bv[4];
#pragma unroll
            for (int a = 0; a < 4; a++) av[a] = *(const f4*)(&As[ty * 4 + a][kk]);
#pragma unroll
            for (int q = 0; q < 4; q++) bv[q] = *(const f4*)(&Bs[kk + q][tx * 4]);
#pragma unroll
            for (int a = 0; a < 4; a++)
#pragma unroll
                for (int q = 0; q < 4; q++) acc[a] += av[a][q] * bv[q];
        }
        __syncthreads();
    }
    const float* t7n = t7 + (size_t)n * CHW;
    const float* t17n = t17 + (size_t)n * CHW;
    float* on = outp + (size_t)n * CHW;
#pragma unroll
    for (int a = 0; a < 4; a++) {
        size_t idx = (size_t)(c0 + ty * 4 + a) * HW + s0 + tx * 4;
        f4 t7v = *(const f4*)(t7n + idx);
        f4 t17v = *(const f4*)(t17n + idx);
        f4 o = acc[a] * S_C + t7v * t17v;
        *(f4*)(on + idx) = o;
    }
}

extern "C" void kernel_launch(void* const* d_in, const int* in_sizes, int n_in,
                              void* d_out, int out_size, void* d_ws, size_t ws_size,
                              hipStream_t stream) {
    const float* x   = (const float*)d_in[0];
    const float* p2  = (const float*)d_in[1];
    const float* w6  = (const float*)d_in[2];
    const float* w7  = (const float*)d_in[3];
    const float* p9  = (const float*)d_in[4];
    const float* p11 = (const float*)d_in[5];
    const float* w12 = (const float*)d_in[6];
    const float* w15 = (const float*)d_in[7];
    const float* p16 = (const float*)d_in[8];
    float* ws = (float*)d_ws;

    float* t3  = ws;                        // 6,422,528 floats each (t3..t17)
    float* t5  = ws + 6422528;
    float* t7  = ws + 12845056;
    float* t17 = ws + 19267584;
    float* t13 = t3;                        // t3 dead after k_t11 / abt(t8)
    float* t8  = ws + 25690112;             // 8*256*256
    float* uu  = ws + 26214400;
    float* t19 = ws + 26738688;
    float* t11 = ws + 27262976;             // 8*3136
    ushort* xp  = (ushort*)(ws + 27288064); // 7,872,512 ushorts (bf16 padded x)
    ushort* w7b = (ushort*)(ws + 31224320); // 589,824 ushorts
    float* outp = (float*)d_out;

    k_t3<<<dim3(6272), dim3(256), 0, stream>>>(x, p2, t3);
    hipMemsetAsync(xp, 0, (size_t)XPAD_ELEMS * 2, stream);
    k_xpad<<<dim3(25088), dim3(256), 0, stream>>>(x, xp);
    k_w7b<<<dim3(2304), dim3(256), 0, stream>>>(w7, w7b);
    k_softmax<<<dim3(Nn * Cc), dim3(256), 0, stream>>>(t3, t5);
    hipMemsetAsync(t8, 0, (size_t)Nn * Cc * Cc * 4, stream);
    hipMemsetAsync(uu, 0, (size_t)Nn * Cc * Cc * 4, stream);
    k_gemm_t7_mfma<<<dim3(25, 2, Nn), dim3(256), 0, stream>>>(xp, w7b, t7);
    k_gemm_t15<<<dim3(49, 4, Nn), dim3(256), 0, stream>>>(x, w15, t3, t17);
    k_gemm_abt<<<dim3(4, 4, Nn * 7), dim3(256), 0, stream>>>(t5, t3, (long)CHW, t8, S_HW);
    k_t11<<<dim3(98), dim3(256), 0, stream>>>(t3, w6, p9, p11, t11);
    k_gemm_abt<<<dim3(4, 4, Nn * 7), dim3(256), 0, stream>>>(t17, p16, 0L, uu, 1.0f);
    k_gemm_t19<<<dim3(4, 4, Nn), dim3(256), 0, stream>>>(uu, t8, t19);
    k_t13<<<dim3(25088), dim3(256), 0, stream>>>(t5, t7, t11, w12, t13);
    k_gemm_out<<<dim3(49, 4, Nn), dim3(256), 0, stream>>>(t19, t13, t7, t17, outp);
}

// Round 3
// 474.704 us; speedup vs baseline: 2.4971x; 1.4403x over previous
//
#include <hip/hip_runtime.h>

#define Nn 8
#define Cc 256
#define C8 32
#define Hh 56
#define Ww 56
#define HW 3136
#define CHW (Cc * HW)          // 802816
#define K9C 2304
#define S_HW (1.0f / 56.0f)    // 1/sqrt(H*W)
#define S_C  0.0625f           // 1/sqrt(C)
#define XPLANE 3844            // 62*62 padded plane
#define XPAD_ELEMS (Nn * Cc * XPLANE)

typedef float f4 __attribute__((ext_vector_type(4)));
typedef unsigned short ushort;
typedef __attribute__((ext_vector_type(4))) unsigned short u16x4;
typedef __attribute__((ext_vector_type(8))) unsigned short u16x8;
typedef __attribute__((ext_vector_type(8))) short short8;   // bf16 MFMA frag
typedef __attribute__((ext_vector_type(4))) float floatx4;

__device__ __forceinline__ ushort f2bf(float f) {   // RNE
    union { float f; unsigned u; } v; v.f = f;
    unsigned r = v.u + 0x7FFF + ((v.u >> 16) & 1);
    return (ushort)(r >> 16);
}
__device__ __forceinline__ float bf2f(ushort u) {
    union { unsigned u; float f; } v; v.u = ((unsigned)u) << 16;
    return v.f;
}

// ---------------------------------------------------- t3 = (p2*x)^2 (+bf16 copy)
__global__ __launch_bounds__(256) void k_t3(const float* __restrict__ x,
                                            const float* __restrict__ p2,
                                            float* __restrict__ t3,
                                            ushort* __restrict__ t3b) {
    int g = blockIdx.x * 256 + threadIdx.x;
    int idx = g * 4;
    int pidx = idx % CHW;
    f4 xv = *(const f4*)(x + idx);
    f4 pv = *(const f4*)(p2 + pidx);
    f4 t = xv * pv;
    f4 q = t * t;
    *(f4*)(t3 + idx) = q;
    u16x4 qb = { f2bf(q[0]), f2bf(q[1]), f2bf(q[2]), f2bf(q[3]) };
    *(u16x4*)(t3b + idx) = qb;
}

// -------------------------------- xp: zero-padded bf16 copy of x (n,c,62,62)
__global__ __launch_bounds__(256) void k_xpad(const float* __restrict__ x,
                                              ushort* __restrict__ xp) {
    int g = blockIdx.x * 256 + threadIdx.x;
    int nc = g / HW;
    int s = g - nc * HW;
    int h = s / Ww, w = s - h * Ww;
    xp[(size_t)nc * XPLANE + (h + 3) * 62 + (w + 3)] = f2bf(x[g]);
}

// -------------------------------- generic fp32 -> bf16 convert
__global__ __launch_bounds__(256) void k_cvt(const float* __restrict__ src,
                                             ushort* __restrict__ dst) {
    int g = blockIdx.x * 256 + threadIdx.x;
    dst[g] = f2bf(src[g]);
}

// ------------------------------------------- t5 = softmax_h(roll(t3,+1h,-1w))
__global__ __launch_bounds__(256) void k_softmax(const float* __restrict__ t3,
                                                 ushort* __restrict__ t5b) {
    __shared__ float ld[HW];
    __shared__ float mx[Ww], rs[Ww];
    int tid = threadIdx.x;
    const float* src = t3 + (size_t)blockIdx.x * HW;
    for (int i = tid; i < HW; i += 256) ld[i] = src[i];
    __syncthreads();
    if (tid < Ww) {
        float m = -1e30f;
        for (int h = 0; h < Hh; h++) m = fmaxf(m, ld[h * Ww + tid]);
        float s = 0.f;
        for (int h = 0; h < Hh; h++) s += __expf(ld[h * Ww + tid] - m);
        mx[tid] = m;
        rs[tid] = 1.0f / s;
    }
    __syncthreads();
    ushort* dst = t5b + (size_t)blockIdx.x * HW;
    for (int i = tid; i < HW; i += 256) {
        int h = i / Ww, w = i - h * Ww;
        int wp = (w + 1 == Ww) ? 0 : w + 1;
        int hp = (h == 0) ? Hh - 1 : h - 1;
        dst[i] = f2bf(__expf(ld[hp * Ww + wp] - mx[wp]) * rs[wp]);
    }
}

// --------------------- t7 = w7 @ im2col(x)  — bf16 MFMA, 128x128 tile
__global__ __launch_bounds__(256) void k_gemm_t7_mfma(const ushort* __restrict__ xp,
                                                      const ushort* __restrict__ w7b,
                                                      float* __restrict__ t7) {
    __shared__ __align__(16) ushort As[128][40];
    __shared__ __align__(16) ushort Bs[128][40];
    int tid = threadIdx.x;
    int lane = tid & 63;
    int ln15 = lane & 15;
    int quad = lane >> 4;
    int wave = tid >> 6;
    int wm64 = (wave >> 1) * 64;
    int wn64 = (wave & 1) * 64;
    int n = blockIdx.z;
    int s0 = blockIdx.x * 128;
    int o0 = blockIdx.y * 128;
    const ushort* xpn = xp + (size_t)n * Cc * XPLANE;

    int s_l = tid & 127;
    int kgrp = (tid >> 7) * 16;
    int s_g = s0 + s_l;
    int sc = s_g < HW ? s_g : HW - 1;
    int h = sc / Ww, w = sc - h * Ww;
    int hw62 = h * 62 + w;

    floatx4 acc[4][4] = {};

    for (int kt = 0; kt < K9C; kt += 32) {
#pragma unroll
        for (int e = 0; e < 2; e++) {
            int lin = tid + e * 256;
            int m = lin >> 2, kq = (lin & 3) * 8;
            u16x8 av = *(const u16x8*)(w7b + (size_t)(o0 + m) * K9C + kt + kq);
            *(u16x8*)(&As[m][kq]) = av;
        }
        ushort vb[16];
#pragma unroll
        for (int u = 0; u < 16; u++) {
            int k = kt + kgrp + u;
            int c = k / 9;
            int r9 = k - 9 * c;
            int i3 = r9 / 3;
            int j3 = r9 - 3 * i3;
            int koff = c * XPLANE + i3 * 186 + j3 * 3;
            vb[u] = xpn[koff + hw62];
        }
        u16x8 b0 = { vb[0], vb[1], vb[2],  vb[3],  vb[4],  vb[5],  vb[6],  vb[7]  };
        u16x8 b1 = { vb[8], vb[9], vb[10], vb[11], vb[12], vb[13], vb[14], vb[15] };
        *(u16x8*)(&Bs[s_l][kgrp])     = b0;
        *(u16x8*)(&Bs[s_l][kgrp + 8]) = b1;
        __syncthreads();

        short8 af[4], bf[4];
#pragma unroll
        for (int a = 0; a < 4; a++)
            af[a] = *(const short8*)(&As[wm64 + a * 16 + ln15][quad * 8]);
#pragma unroll
        for (int b = 0; b < 4; b++)
            bf[b] = *(const short8*)(&Bs[wn64 + b * 16 + ln15][quad * 8]);
#pragma unroll
        for (int a = 0; a < 4; a++)
#pragma unroll
            for (int b = 0; b < 4; b++)
                acc[a][b] = __builtin_amdgcn_mfma_f32_16x16x32_bf16(
                    af[a], bf[b], acc[a][b], 0, 0, 0);
        __syncthreads();
    }

    float* t7n = t7 + (size_t)n * CHW;
#pragma unroll
    for (int a = 0; a < 4; a++) {
        int obase = o0 + wm64 + a * 16 + quad * 4;
#pragma unroll
        for (int b = 0; b < 4; b++) {
            int s = s0 + wn64 + b * 16 + ln15;
            if (s < HW) {
#pragma unroll
                for (int r = 0; r < 4; r++)
                    t7n[(size_t)(obase + r) * HW + s] = acc[a][b][r];
            }
        }
    }
}

// ---------- t17b = bf16(t3 - w15 @ roll(x,+1,h))  — bf16 MFMA, 128x128 tile
__global__ __launch_bounds__(256) void k_gemm_t15_mfma(const float* __restrict__ x,
                                                       const ushort* __restrict__ w15b,
                                                       const float* __restrict__ t3,
                                                       ushort* __restrict__ t17b) {
    __shared__ __align__(16) ushort As[128][40];
    __shared__ __align__(16) ushort Bs[128][40];
    int tid = threadIdx.x;
    int lane = tid & 63;
    int ln15 = lane & 15;
    int quad = lane >> 4;
    int wave = tid >> 6;
    int wm64 = (wave >> 1) * 64;
    int wn64 = (wave & 1) * 64;
    int n = blockIdx.z;
    int s0 = blockIdx.x * 128;
    int o0 = blockIdx.y * 128;
    const float* xn = x + (size_t)n * CHW;

    floatx4 acc[4][4] = {};

    for (int kt = 0; kt < Cc; kt += 32) {
        // A: w15b rows o0..+127, k kt..+31 (u16x8 contiguous)
#pragma unroll
        for (int e = 0; e < 2; e++) {
            int lin = tid + e * 256;
            int m = lin >> 2, kq = (lin & 3) * 8;
            *(u16x8*)(&As[m][kq]) =
                *(const u16x8*)(w15b + (size_t)(o0 + m) * Cc + kt + kq);
        }
        // B: rolled x, transpose-in-LDS: Bs[s][c]
#pragma unroll
        for (int e = 0; e < 4; e++) {
            int lin = tid + e * 256;             // 0..1023
            int c_l = lin >> 5;                  // 0..31
            int s4 = (lin & 31) * 4;
            int s = s0 + s4;
            int sc = s < HW ? s : HW - 4;
            int h = sc / Ww;
            int s_src = (h == 0) ? sc + 3080 : sc - 56;
            f4 v = *(const f4*)(xn + (size_t)(kt + c_l) * HW + s_src);
            Bs[s4 + 0][c_l] = f2bf(v[0]);
            Bs[s4 + 1][c_l] = f2bf(v[1]);
            Bs[s4 + 2][c_l] = f2bf(v[2]);
            Bs[s4 + 3][c_l] = f2bf(v[3]);
        }
        __syncthreads();

        short8 af[4], bf[4];
#pragma unroll
        for (int a = 0; a < 4; a++)
            af[a] = *(const short8*)(&As[wm64 + a * 16 + ln15][quad * 8]);
#pragma unroll
        for (int b = 0; b < 4; b++)
            bf[b] = *(const short8*)(&Bs[wn64 + b * 16 + ln15][quad * 8]);
#pragma unroll
        for (int a = 0; a < 4; a++)
#pragma unroll
            for (int b = 0; b < 4; b++)
                acc[a][b] = __builtin_amdgcn_mfma_f32_16x16x32_bf16(
                    af[a], bf[b], acc[a][b], 0, 0, 0);
        __syncthreads();
    }

    const float* t3n = t3 + (size_t)n * CHW;
    ushort* t17n = t17b + (size_t)n * CHW;
#pragma unroll
    for (int a = 0; a < 4; a++) {
        int obase = o0 + wm64 + a * 16 + quad * 4;
#pragma unroll
        for (int b = 0; b < 4; b++) {
            int s = s0 + wn64 + b * 16 + ln15;
            if (s < HW) {
#pragma unroll
                for (int r = 0; r < 4; r++) {
                    size_t idx = (size_t)(obase + r) * HW + s;
                    t17n[idx] = f2bf(t3n[idx] - acc[a][b][r]);
                }
            }
        }
    }
}

// ----- out[n,c,d] += scale * sum_s A[n,c,s]*B[(n,)d,s] — bf16 MFMA, split-K=7
__global__ __launch_bounds__(256) void k_gemm_abt_mfma(const ushort* __restrict__ A,
                                                       const ushort* __restrict__ B,
                                                       long Bn,
                                                       float* __restrict__ outp,
                                                       float scale) {
    __shared__ __align__(16) ushort As[128][40];
    __shared__ __align__(16) ushort Bs[128][40];
    int tid = threadIdx.x;
    int lane = tid & 63;
    int ln15 = lane & 15;
    int quad = lane >> 4;
    int wave = tid >> 6;
    int wm64 = (wave >> 1) * 64;
    int wn64 = (wave & 1) * 64;
    int z = blockIdx.z;
    int n = z / 7, ks = z - n * 7;
    int d0 = blockIdx.x * 128;
    int c0 = blockIdx.y * 128;
    const ushort* An = A + (size_t)n * CHW;
    const ushort* Bb = B + (size_t)n * Bn;

    floatx4 acc[4][4] = {};
    int kbeg = ks * 448;

    for (int kt = kbeg; kt < kbeg + 448; kt += 32) {
#pragma unroll
        for (int e = 0; e < 2; e++) {
            int lin = tid + e * 256;
            int m = lin >> 2, kq = (lin & 3) * 8;
            *(u16x8*)(&As[m][kq]) =
                *(const u16x8*)(An + (size_t)(c0 + m) * HW + kt + kq);
            *(u16x8*)(&Bs[m][kq]) =
                *(const u16x8*)(Bb + (size_t)(d0 + m) * HW + kt + kq);
        }
        __syncthreads();

        short8 af[4], bf[4];
#pragma unroll
        for (int a = 0; a < 4; a++)
            af[a] = *(const short8*)(&As[wm64 + a * 16 + ln15][quad * 8]);
#pragma unroll
        for (int b = 0; b < 4; b++)
            bf[b] = *(const short8*)(&Bs[wn64 + b * 16 + ln15][quad * 8]);
#pragma unroll
        for (int a = 0; a < 4; a++)
#pragma unroll
            for (int b = 0; b < 4; b++)
                acc[a][b] = __builtin_amdgcn_mfma_f32_16x16x32_bf16(
                    af[a], bf[b], acc[a][b], 0, 0, 0);
        __syncthreads();
    }

    float* on = outp + (size_t)n * (Cc * Cc);
#pragma unroll
    for (int a = 0; a < 4; a++) {
        int cbase = c0 + wm64 + a * 16 + quad * 4;
#pragma unroll
        for (int b = 0; b < 4; b++) {
            int d = d0 + wn64 + b * 16 + ln15;
#pragma unroll
            for (int r = 0; r < 4; r++)
                atomicAdd(&on[(size_t)(cbase + r) * Cc + d], acc[a][b][r] * scale);
        }
    }
}

// ---------------- t19Tb[c',d] = bf16(s_hw * sum_b u[n,d? ] ... ) transposed store
// computes T[c][d] = s_hw * sum_b u[c][b]*t8[b][d], stores bf16 at [d][c]
__global__ __launch_bounds__(256) void k_gemm_t19(const float* __restrict__ u,
                                                  const float* __restrict__ t8,
                                                  ushort* __restrict__ t19Tb) {
    __shared__ float As[64][20];
    __shared__ float Bs[16][68];
    int tid = threadIdx.x;
    int tx = tid & 15, ty = tid >> 4;
    int n = blockIdx.z;
    int d0 = blockIdx.x * 64;
    int c0 = blockIdx.y * 64;
    const float* un = u + (size_t)n * Cc * Cc;
    const float* t8n = t8 + (size_t)n * Cc * Cc;
    f4 acc[4] = {};
    for (int kt = 0; kt < Cc; kt += 16) {
        int lin = tid * 4;
        {
            int r = lin >> 4, kq = lin & 15;
            *(f4*)(&As[r][kq]) = *(const f4*)(un + (size_t)(c0 + r) * Cc + kt + kq);
        }
        {
            int kk = lin >> 6, col = lin & 63;
            *(f4*)(&Bs[kk][col]) = *(const f4*)(t8n + (size_t)(kt + kk) * Cc + d0 + col);
        }
        __syncthreads();
#pragma unroll
        for (int kk = 0; kk < 16; kk += 4) {
            f4 av[4], bv[4];
#pragma unroll
            for (int a = 0; a < 4; a++) av[a] = *(const f4*)(&As[ty * 4 + a][kk]);
#pragma unroll
            for (int q = 0; q < 4; q++) bv[q] = *(const f4*)(&Bs[kk + q][tx * 4]);
#pragma unroll
            for (int a = 0; a < 4; a++)
#pragma unroll
                for (int q = 0; q < 4; q++) acc[a] += av[a][q] * bv[q];
        }
        __syncthreads();
    }
    ushort* on = t19Tb + (size_t)n * Cc * Cc;
#pragma unroll
    for (int a = 0; a < 4; a++) {
        int c = c0 + ty * 4 + a;
#pragma unroll
        for (int j = 0; j < 4; j++)
            on[(size_t)(d0 + tx * 4 + j) * Cc + c] = f2bf(acc[a][j] * S_HW);
    }
}

// -------- t11[n,s] = sum_b p11[b]*p9[b,s]*(sum_c w6[b,c]*t3[n,c,s])
__global__ __launch_bounds__(256) void k_t11(const float* __restrict__ t3,
                                             const float* __restrict__ w6,
                                             const float* __restrict__ p9,
                                             const float* __restrict__ p11,
                                             float* __restrict__ t11) {
    __shared__ float w6s[C8 * Cc];
    int tid = threadIdx.x;
    for (int i = tid; i < C8 * Cc; i += 256) w6s[i] = w6[i];
    __syncthreads();
    int g = blockIdx.x * 256 + tid;
    int n = g / HW;
    int s = g - n * HW;
    const float* t3n = t3 + (size_t)n * CHW + s;
    float acc[C8] = {};
    for (int c = 0; c < Cc; c += 4) {
        float v0 = t3n[(c + 0) * HW];
        float v1 = t3n[(c + 1) * HW];
        float v2 = t3n[(c + 2) * HW];
        float v3 = t3n[(c + 3) * HW];
#pragma unroll
        for (int b = 0; b < C8; b++) {
            f4 wv = *(const f4*)(&w6s[b * Cc + c]);
            acc[b] += wv[0] * v0 + wv[1] * v1 + wv[2] * v2 + wv[3] * v3;
        }
    }
    float r = 0.f;
#pragma unroll
    for (int b = 0; b < C8; b++) r += p11[b] * p9[b * HW + s] * acc[b];
    t11[g] = r;
}

// ------- t13b = bf16(t11 - depthwise_conv(max(t5,t7), w12))
__global__ __launch_bounds__(256) void k_t13(const ushort* __restrict__ t5b,
                                             const float* __restrict__ t7,
                                             const float* __restrict__ t11,
                                             const float* __restrict__ w12,
                                             ushort* __restrict__ t13b) {
    int g = blockIdx.x * 256 + threadIdx.x;
    int s = g % HW;
    int nc = g / HW;
    int c = nc % Cc;
    int n = nc / Cc;
    int h = s / Ww, w = s - h * Ww;
    float sum = 0.f;
#pragma unroll
    for (int kh = 0; kh < 3; kh++) {
        int hh = h - 2 + 2 * kh;
        if ((unsigned)hh < (unsigned)Hh) {
            size_t idx = (size_t)nc * HW + hh * Ww + w;
            float t10 = fmaxf(bf2f(t5b[idx]), t7[idx]);
            sum += w12[c * 3 + kh] * t10;
        }
    }
    t13b[g] = f2bf(t11[(size_t)n * HW + s] - sum);
}

// -------- out[c,s] = s_c * sum_d t19T[c,d]*t13[d,s] + t7*t17 — bf16 MFMA
__global__ __launch_bounds__(256) void k_gemm_out_mfma(const ushort* __restrict__ t19Tb,
                                                       const ushort* __restrict__ t13b,
                                                       const float* __restrict__ t7,
                                                       const ushort* __restrict__ t17b,
                                                       float* __restrict__ outp) {
    __shared__ __align__(16) ushort As[128][40];
    __shared__ __align__(16) ushort Bs[128][40];
    int tid = threadIdx.x;
    int lane = tid & 63;
    int ln15 = lane & 15;
    int quad = lane >> 4;
    int wave = tid >> 6;
    int wm64 = (wave >> 1) * 64;
    int wn64 = (wave & 1) * 64;
    int n = blockIdx.z;
    int s0 = blockIdx.x * 128;
    int c0 = blockIdx.y * 128;
    const ushort* An = t19Tb + (size_t)n * Cc * Cc;
    const ushort* t13n = t13b + (size_t)n * CHW;

    floatx4 acc[4][4] = {};

    for (int kt = 0; kt < Cc; kt += 32) {
        // A: t19Tb rows c0..+127, k=d contiguous
#pragma unroll
        for (int e = 0; e < 2; e++) {
            int lin = tid + e * 256;
            int m = lin >> 2, kq = (lin & 3) * 8;
            *(u16x8*)(&As[m][kq]) =
                *(const u16x8*)(An + (size_t)(c0 + m) * Cc + kt + kq);
        }
        // B: t13b [d][s] -> Bs[s][d] transpose-in-LDS
#pragma unroll
        for (int e = 0; e < 2; e++) {
            int lin = tid + e * 256;             // 0..511
            int d_l = lin >> 4;                  // 0..31
            int s8 = (lin & 15) * 8;
            int s = s0 + s8;
            int sc = s <= HW - 8 ? s : HW - 8;
            u16x8 v = *(const u16x8*)(t13n + (size_t)(kt + d_l) * HW + sc);
#pragma unroll
            for (int j = 0; j < 8; j++) Bs[s8 + j][d_l] = v[j];
        }
        __syncthreads();

        short8 af[4], bf[4];
#pragma unroll
        for (int a = 0; a < 4; a++)
            af[a] = *(const short8*)(&As[wm64 + a * 16 + ln15][quad * 8]);
#pragma unroll
        for (int b = 0; b < 4; b++)
            bf[b] = *(const short8*)(&Bs[wn64 + b * 16 + ln15][quad * 8]);
#pragma unroll
        for (int a = 0; a < 4; a++)
#pragma unroll
            for (int b = 0; b < 4; b++)
                acc[a][b] = __builtin_amdgcn_mfma_f32_16x16x32_bf16(
                    af[a], bf[b], acc[a][b], 0, 0, 0);
        __syncthreads();
    }

    const float* t7n = t7 + (size_t)n * CHW;
    const ushort* t17n = t17b + (size_t)n * CHW;
    float* on = outp + (size_t)n * CHW;
#pragma unroll
    for (int a = 0; a < 4; a++) {
        int cbase = c0 + wm64 + a * 16 + quad * 4;
#pragma unroll
        for (int b = 0; b < 4; b++) {
            int s = s0 + wn64 + b * 16 + ln15;
            if (s < HW) {
#pragma unroll
                for (int r = 0; r < 4; r++) {
                    size_t idx = (size_t)(cbase + r) * HW + s;
                    on[idx] = acc[a][b][r] * S_C + t7n[idx] * bf2f(t17n[idx]);
                }
            }
        }
    }
}

extern "C" void kernel_launch(void* const* d_in, const int* in_sizes, int n_in,
                              void* d_out, int out_size, void* d_ws, size_t ws_size,
                              hipStream_t stream) {
    const float* x   = (const float*)d_in[0];
    const float* p2  = (const float*)d_in[1];
    const float* w6  = (const float*)d_in[2];
    const float* w7  = (const float*)d_in[3];
    const float* p9  = (const float*)d_in[4];
    const float* p11 = (const float*)d_in[5];
    const float* w12 = (const float*)d_in[6];
    const float* w15 = (const float*)d_in[7];
    const float* p16 = (const float*)d_in[8];
    float* ws = (float*)d_ws;

    float* t3  = ws;                        // 6422528
    float* t7  = ws + 6422528;              // 6422528
    float* t8  = ws + 12845056;             // 524288
    float* uu  = ws + 13369344;             // 524288
    float* t11 = ws + 13893632;             // 25600
    ushort* ub  = (ushort*)(ws + 13919232);
    ushort* t5b   = ub;                     // 6422528
    ushort* t3b   = ub + 6422528;           // 6422528
    ushort* t17b  = ub + 12845056;          // 6422528
    ushort* t13b  = ub + 19267584;          // 6422528
    ushort* xp    = ub + 25690112;          // 7872512
    ushort* w7b   = ub + 33562624;          // 589824
    ushort* w15b  = ub + 34152448;          // 65536
    ushort* p16b  = ub + 34217984;          // 802816
    ushort* t19Tb = ub + 35020800;          // 524288
    float* outp = (float*)d_out;

    k_t3<<<dim3(6272), dim3(256), 0, stream>>>(x, p2, t3, t3b);
    hipMemsetAsync(xp, 0, (size_t)XPAD_ELEMS * 2, stream);
    k_xpad<<<dim3(25088), dim3(256), 0, stream>>>(x, xp);
    k_cvt<<<dim3(2304), dim3(256), 0, stream>>>(w7, w7b);
    k_cvt<<<dim3(256),  dim3(256), 0, stream>>>(w15, w15b);
    k_cvt<<<dim3(3136), dim3(256), 0, stream>>>(p16, p16b);
    k_softmax<<<dim3(Nn * Cc), dim3(256), 0, stream>>>(t3, t5b);
    hipMemsetAsync(t8, 0, (size_t)Nn * Cc * Cc * 4, stream);
    hipMemsetAsync(uu, 0, (size_t)Nn * Cc * Cc * 4, stream);
    k_gemm_t7_mfma<<<dim3(25, 2, Nn), dim3(256), 0, stream>>>(xp, w7b, t7);
    k_gemm_t15_mfma<<<dim3(25, 2, Nn), dim3(256), 0, stream>>>(x, w15b, t3, t17b);
    k_gemm_abt_mfma<<<dim3(2, 2, Nn * 7), dim3(256), 0, stream>>>(t5b, t3b, (long)CHW, t8, S_HW);
    k_t11<<<dim3(98), dim3(256), 0, stream>>>(t3, w6, p9, p11, t11);
    k_gemm_abt_mfma<<<dim3(2, 2, Nn * 7), dim3(256), 0, stream>>>(t17b, p16b, 0L, uu, 1.0f);
    k_gemm_t19<<<dim3(4, 4, Nn), dim3(256), 0, stream>>>(uu, t8, t19Tb);
    k_t13<<<dim3(25088), dim3(256), 0, stream>>>(t5b, t7, t11, w12, t13b);
    k_gemm_out_mfma<<<dim3(25, 2, Nn), dim3(256), 0, stream>>>(t19Tb, t13b, t7, t17b, outp);
}